// Round 12
// baseline (192.047 us; speedup 1.0000x reference)
//
#include <hip/hip_runtime.h>
#include <hip/hip_bf16.h>

#define S_LEN 2048
#define D_DIM 128
#define QBLK 128
#define KVBLK 64
#define NT (S_LEN / KVBLK)          // 32 tiles of 64 kv
#define KCHUNK 16384                // bytes per K tile image (64 rows x 256B)
#define VCHUNK 16384                // bytes per V^T tile image (128 d x 128B)
#define PRE_BYTES ((size_t)64 * NT * (KCHUNK + VCHUNK))   // 67108864

typedef __attribute__((ext_vector_type(8))) short short8v;
typedef __attribute__((ext_vector_type(16))) float f32x16;

static __device__ __forceinline__ unsigned f2bf2(float lo, float hi) {
    float2 f2; f2.x = lo; f2.y = hi;
    __hip_bfloat162 h2 = __float22bfloat162_rn(f2);   // v_cvt_pk_bf16_f32
    unsigned r;
    __builtin_memcpy(&r, &h2, 4);
    return r;
}

// SSA-pure permlane32_swap: new_a = {a.row0, b.row0}, new_b = {a.row1, b.row1}
static __device__ __forceinline__ void plswap(unsigned& a, unsigned& b) {
    auto r = __builtin_amdgcn_permlane32_swap(a, b, false, false);
    a = r[0]; b = r[1];
}
static __device__ __forceinline__ float plswap_sum(float x) {
    unsigned a = __float_as_uint(x), b = a;
    plswap(a, b);
    return __uint_as_float(a) + __uint_as_float(b);
}

static __device__ __forceinline__ void gload16(const void* g, void* l) {
    __builtin_amdgcn_global_load_lds(
        (const __attribute__((address_space(1))) unsigned int*)g,
        (__attribute__((address_space(3))) unsigned int*)l,
        16, 0, 0);
}

// stage one 16KB pre-swizzled chunk: wave-uniform LDS base, per-lane global addr
static __device__ __forceinline__ void stage16k(const unsigned char* g, unsigned char* l,
                                                int wv, int lane) {
#pragma unroll
    for (int i = 0; i < 4; ++i) {
        const int off = (wv * 4 + i) * 1024;
        gload16(g + off + lane * 16, l + off);
    }
}

// ============================================================================
// Kernel 1 (round-4 proven): pre-convert K -> bf16 swizzled image, V -> V^T
// K chunk: unit o=row*16+bs holds K[row][8b..], b=(bs&8)|((bs^row)&7)
// V chunk: unit o=d*8+bs holds V^T[d][8b..],   b=(bs^d)&7
// ============================================================================
#define VTS 133

__global__ __launch_bounds__(256) void preconv(
    const float* __restrict__ Kp, const float* __restrict__ Vp,
    unsigned short* __restrict__ Ko, unsigned short* __restrict__ Vo)
{
    __shared__ float vt[64 * VTS];
    const int tid = threadIdx.x;
    const int blk = blockIdx.x;          // bh*32 + t
    const size_t gbase = (size_t)(blk >> 5) * S_LEN * D_DIM + (size_t)(blk & 31) * KVBLK * D_DIM;

    // stage V fp32 64x128 tile into LDS
#pragma unroll
    for (int i = 0; i < 8; ++i) {
        int idx = (tid + 256 * i) * 4;
        int row = idx >> 7, col = idx & 127;
        float4 v4 = *(const float4*)(Vp + gbase + idx);
        float* d = &vt[row * VTS + col];
        d[0] = v4.x; d[1] = v4.y; d[2] = v4.z; d[3] = v4.w;
    }

    // K: direct convert + swizzle-store
    unsigned short* kout = Ko + (size_t)blk * 8192;
#pragma unroll
    for (int i = 0; i < 4; ++i) {
        int o = tid + 256 * i;
        int row = o >> 4, bs = o & 15;
        int b = (bs & 8) | ((bs ^ row) & 7);
        const float* gp = Kp + gbase + row * D_DIM + 8 * b;
        float4 x = *(const float4*)gp;
        float4 y = *(const float4*)(gp + 4);
        uint4 w;
        w.x = f2bf2(x.x, x.y); w.y = f2bf2(x.z, x.w);
        w.z = f2bf2(y.x, y.y); w.w = f2bf2(y.z, y.w);
        *(uint4*)(kout + o * 8) = w;
    }
    __syncthreads();

    // V^T: gather columns from LDS, swizzle-store
    unsigned short* vout = Vo + (size_t)blk * 8192;
#pragma unroll
    for (int i = 0; i < 4; ++i) {
        int o = tid + 256 * i;
        int d = o >> 3, bs = o & 7;
        int b = (bs ^ d) & 7;
        const float* c0 = &vt[(8 * b) * VTS + d];
        uint4 w;
        w.x = f2bf2(c0[0 * VTS], c0[1 * VTS]);
        w.y = f2bf2(c0[2 * VTS], c0[3 * VTS]);
        w.z = f2bf2(c0[4 * VTS], c0[5 * VTS]);
        w.w = f2bf2(c0[6 * VTS], c0[7 * VTS]);
        *(uint4*)(vout + o * 8) = w;
    }
}

// ============================================================================
// Kernel 2: fused attention, KVBLK=64, fixed-max softmax, permlane PV.
// NO setprio fences in the loop: phases ordered so the scheduler can
// interleave {QK(B) || exp(A)} and {PV(A) || exp(B)} within each wave.
// LDS: K dbuf 32KB | V dbuf 32KB | bias 8KB = 73728
// ============================================================================
#define ASMEM (32768 + 32768 + 8192)

__global__ __launch_bounds__(256, 3) void sdpa_fwd_pre(
    const float* __restrict__ Qp, const unsigned short* __restrict__ Kpre,
    const unsigned short* __restrict__ Vpre, const int* __restrict__ Mp,
    float* __restrict__ Op)
{
    extern __shared__ unsigned char smem[];
    unsigned char* KbB = smem;                     // [2][16384]
    unsigned char* VbB = smem + 32768;             // [2][16384]
    float* blds = (float*)(smem + 65536);          // [2048] additive bias (log2 units)

    const int tid  = threadIdx.x;
    const int lane = tid & 63;
    const int wv   = tid >> 6;
    const int h    = lane >> 5;
    const int c31  = lane & 31;
    const int hrx  = h ^ (c31 & 7);
    // XCD-aware bijective swizzle (1024 % 8 == 0)
    const int lbid = ((blockIdx.x & 7) << 7) | (blockIdx.x >> 3);
    const int bh   = lbid >> 4;
    const int q0   = (lbid & 15) * QBLK;
    const int bb   = bh >> 4;
    const size_t base = (size_t)bh * S_LEN * D_DIM;
    const unsigned char* Kg = (const unsigned char*)Kpre + (size_t)bh * (NT * KCHUNK);
    const unsigned char* Vg = (const unsigned char*)Vpre + (size_t)bh * (NT * VCHUNK);

    constexpr float SC   = 0.08838834764831845f * 1.4426950408889634f; // 1/sqrt(128)*log2e
    constexpr float NEGB = -1.4426950408889634e9f;                     // -1e9*log2e
    constexpr float M2   = 16.0f;  // fixed softmax stabilizer (log2 units)

    // ---- mask -> additive bias table: visible -> -M2, masked -> NEGB ----
    {
        const int* mp = Mp + bb * S_LEN;
#pragma unroll
        for (int i = 0; i < S_LEN / 256; ++i)
            blds[tid + 256 * i] = mp[tid + 256 * i] ? -M2 : NEGB;
    }

    // ---- Q fragments pre-scaled by SC: lane holds Q[q0+32*wv+c31][16*kk+8*h+j] ----
    short8v qf[8];
    {
        const float* qrp = Qp + base + (size_t)(q0 + 32 * wv + c31) * D_DIM;
#pragma unroll
        for (int kk = 0; kk < 8; ++kk) {
            float4 x = *(const float4*)(qrp + 16 * kk + 8 * h);
            float4 y = *(const float4*)(qrp + 16 * kk + 8 * h + 4);
            uint4 w;
            w.x = f2bf2(x.x * SC, x.y * SC); w.y = f2bf2(x.z * SC, x.w * SC);
            w.z = f2bf2(y.x * SC, y.y * SC); w.w = f2bf2(y.z * SC, y.w * SC);
            *(uint4*)&qf[kk] = w;
        }
    }

    // ---- prologue: stage tile 0 ----
    stage16k(Kg, KbB, wv, lane);
    stage16k(Vg, VbB, wv, lane);
    __syncthreads();

    f32x16 acc[4];   // O^T: rows d = 32*dt + rowmap, col q = c31
#pragma unroll
    for (int dt = 0; dt < 4; ++dt)
#pragma unroll
        for (int i = 0; i < 16; ++i) acc[dt][i] = 0.f;

    float lpA = 0.f, lpB = 0.f;
    int cur = 0;

#pragma unroll 1
    for (int t0 = 0; t0 < NT; ++t0) {
        const unsigned char* KcB = KbB + cur * KCHUNK;
        const unsigned char* VcB = VbB + cur * VCHUNK;

        // ---- issue next tile's gload_lds ----
        if (t0 + 1 < NT) {
            stage16k(Kg + (size_t)(t0 + 1) * KCHUNK, KbB + (cur ^ 1) * KCHUNK, wv, lane);
            stage16k(Vg + (size_t)(t0 + 1) * VCHUNK, VbB + (cur ^ 1) * VCHUNK, wv, lane);
        }

        // ---- C-init from bias (kv = 32c + 8t4 + 4h + j), both halves ----
        f32x16 sA, sB;
        {
            const float* bp = blds + t0 * KVBLK + 4 * h;
#pragma unroll
            for (int t4 = 0; t4 < 4; ++t4) {
                float4 b4 = *(const float4*)(bp + 8 * t4);
                sA[4 * t4 + 0] = b4.x; sA[4 * t4 + 1] = b4.y;
                sA[4 * t4 + 2] = b4.z; sA[4 * t4 + 3] = b4.w;
                float4 b5 = *(const float4*)(bp + 32 + 8 * t4);
                sB[4 * t4 + 0] = b5.x; sB[4 * t4 + 1] = b5.y;
                sB[4 * t4 + 2] = b5.z; sB[4 * t4 + 3] = b5.w;
            }
        }

        const unsigned char* rowpA = KcB + (c31 << 8);
        const unsigned char* rowpB = KcB + ((32 + c31) << 8);

        // ---- phase 1: QK(A) ----
#pragma unroll
        for (int kk = 0; kk < 8; ++kk) {
            const int bs = ((2 * kk) & 8) | (((2 * kk) & 7) ^ hrx);
            short8v kfA = *(const short8v*)(rowpA + (bs << 4));
            sA = __builtin_amdgcn_mfma_f32_32x32x16_bf16(kfA, qf[kk], sA, 0, 0, 0);
        }

        // ---- phase 2: QK(B)  ||  exp/pack(A)  (independent; scheduler mixes) ----
#pragma unroll
        for (int kk = 0; kk < 8; ++kk) {
            const int bs = ((2 * kk) & 8) | (((2 * kk) & 7) ^ hrx);
            short8v kfB = *(const short8v*)(rowpB + (bs << 4));
            sB = __builtin_amdgcn_mfma_f32_32x32x16_bf16(kfB, qf[kk], sB, 0, 0, 0);
        }
        unsigned w0A[4], w1A[4];
        {
            float l0 = 0.f, l1 = 0.f;
#pragma unroll
            for (int t4 = 0; t4 < 4; ++t4) {
                float e0 = __builtin_amdgcn_exp2f(sA[4 * t4 + 0]);
                float e1 = __builtin_amdgcn_exp2f(sA[4 * t4 + 1]);
                float e2 = __builtin_amdgcn_exp2f(sA[4 * t4 + 2]);
                float e3 = __builtin_amdgcn_exp2f(sA[4 * t4 + 3]);
                w0A[t4] = f2bf2(e0, e1);
                w1A[t4] = f2bf2(e2, e3);
                l0 += e0 + e1; l1 += e2 + e3;
            }
            lpA += l0 + l1;
        }

        // ---- phase 3: PV(ks=0,1 on A)  ||  exp/pack(B) ----
        unsigned w0B[4], w1B[4];
        {
            float l0 = 0.f, l1 = 0.f;
#pragma unroll
            for (int t4 = 0; t4 < 4; ++t4) {
                float f0 = __builtin_amdgcn_exp2f(sB[4 * t4 + 0]);
                float f1 = __builtin_amdgcn_exp2f(sB[4 * t4 + 1]);
                float f2 = __builtin_amdgcn_exp2f(sB[4 * t4 + 2]);
                float f3 = __builtin_amdgcn_exp2f(sB[4 * t4 + 3]);
                w0B[t4] = f2bf2(f0, f1);
                w1B[t4] = f2bf2(f2, f3);
                l0 += f0 + f1; l1 += f2 + f3;
            }
            lpB += l0 + l1;
        }
#pragma unroll
        for (int ks = 0; ks < 2; ++ks) {
            unsigned ax = w0A[2 * ks], bx = w0A[2 * ks + 1];
            plswap(ax, bx);
            unsigned ay = w1A[2 * ks], by = w1A[2 * ks + 1];
            plswap(ay, by);
            uint4 pw; pw.x = ax; pw.y = ay; pw.z = bx; pw.w = by;
            short8v pfv = *(short8v*)&pw;
            const int bs = ((2 * ks) ^ hrx) & 7;
#pragma unroll
            for (int dt = 0; dt < 4; ++dt) {
                short8v vf = *(const short8v*)(VcB + ((32 * dt + c31) << 7) + (bs << 4));
                acc[dt] = __builtin_amdgcn_mfma_f32_32x32x16_bf16(vf, pfv, acc[dt], 0, 0, 0);
            }
        }

        // ---- phase 4: PV(ks=2,3 on B) ----
#pragma unroll
        for (int ks = 2; ks < 4; ++ks) {
            const int kkl = ks & 1;
            unsigned ax = w0B[2 * kkl], bx = w0B[2 * kkl + 1];
            plswap(ax, bx);
            unsigned ay = w1B[2 * kkl], by = w1B[2 * kkl + 1];
            plswap(ay, by);
            uint4 pw; pw.x = ax; pw.y = ay; pw.z = bx; pw.w = by;
            short8v pfv = *(short8v*)&pw;
            const int bs = ((2 * ks) ^ hrx) & 7;
#pragma unroll
            for (int dt = 0; dt < 4; ++dt) {
                short8v vf = *(const short8v*)(VcB + ((32 * dt + c31) << 7) + (bs << 4));
                acc[dt] = __builtin_amdgcn_mfma_f32_32x32x16_bf16(vf, pfv, acc[dt], 0, 0, 0);
            }
        }

        __syncthreads();   // drains vmcnt (prefetch landed) + all reads done
        cur ^= 1;
    }

    // ---- combine half-wave partial denoms; epilogue transpose + store ----
    const float linv = 1.0f / plswap_sum(lpA + lpB);
    float* sw = (float*)(smem + wv * (32 * 68 * 4));
#pragma unroll
    for (int ph = 0; ph < 2; ++ph) {
#pragma unroll
        for (int dp = 0; dp < 2; ++dp) {
            const int dtg = 2 * ph + dp;
#pragma unroll
            for (int r = 0; r < 16; ++r) {
                int dloc = 32 * dp + (r & 3) + 8 * (r >> 2) + 4 * h;
                sw[c31 * 68 + dloc] = acc[dtg][r] * linv;
            }
        }
#pragma unroll
        for (int it = 0; it < 8; ++it) {
            int f4 = lane + 64 * it;
            int qq = f4 >> 4, c4 = f4 & 15;
            float4 val = *(const float4*)&sw[qq * 68 + 4 * c4];
            *(float4*)(Op + base + (size_t)(q0 + 32 * wv + qq) * D_DIM + 64 * ph + 4 * c4) = val;
        }
    }
}

// ============================================================================
// Fallback (round-3 kernel, only if ws_size too small) — own constants
// ============================================================================
#define FBKV 64
#define FBNT (S_LEN / FBKV)
#define FBQB 128
#define KSTRIDE 136
#define VSTRIDE 72
#define KELEMS (FBKV * KSTRIDE)
#define VELEMS (D_DIM * VSTRIDE)
#define KBYTES (2 * KELEMS * 2)
#define VBYTES (2 * VELEMS * 2)
#define FBSMEM (KBYTES + VBYTES + S_LEN * 4)

struct KReg { float4 a[4][2]; };
struct VReg { float4 a[2][4]; };

static __device__ __forceinline__ void load_K(KReg& kr, const float* Kbase,
                                              int kv0, int kr0, int kc8) {
#pragma unroll
    for (int i = 0; i < 4; ++i) {
        const float* gp = Kbase + (size_t)(kv0 + kr0 + 16 * i) * D_DIM + 8 * kc8;
        kr.a[i][0] = *(const float4*)gp;
        kr.a[i][1] = *(const float4*)(gp + 4);
    }
}
static __device__ __forceinline__ void write_K(const KReg& kr, unsigned short* Kn,
                                               int kr0, int kc8) {
#pragma unroll
    for (int i = 0; i < 4; ++i) {
        uint4 w;
        w.x = f2bf2(kr.a[i][0].x, kr.a[i][0].y);
        w.y = f2bf2(kr.a[i][0].z, kr.a[i][0].w);
        w.z = f2bf2(kr.a[i][1].x, kr.a[i][1].y);
        w.w = f2bf2(kr.a[i][1].z, kr.a[i][1].w);
        *(uint4*)&Kn[(kr0 + 16 * i) * KSTRIDE + 8 * kc8] = w;
    }
}
static __device__ __forceinline__ void load_V(VReg& vr, const float* Vbase,
                                              int kv0, int vkq, int vdg) {
#pragma unroll
    for (int ii = 0; ii < 2; ++ii)
#pragma unroll
        for (int r = 0; r < 4; ++r)
            vr.a[ii][r] = *(const float4*)(Vbase + (size_t)(kv0 + 4 * vkq + 32 * ii + r) * D_DIM + 4 * vdg);
}
static __device__ __forceinline__ void write_V(const VReg& vr, unsigned short* Vn,
                                               int vkq, int vdg) {
#pragma unroll
    for (int ii = 0; ii < 2; ++ii) {
        const int kvb = 4 * vkq + 32 * ii;
        const int d0  = 4 * vdg;
        uint2 u;
        u.x = f2bf2(vr.a[ii][0].x, vr.a[ii][1].x); u.y = f2bf2(vr.a[ii][2].x, vr.a[ii][3].x);
        *(uint2*)&Vn[(d0 + 0) * VSTRIDE + kvb] = u;
        u.x = f2bf2(vr.a[ii][0].y, vr.a[ii][1].y); u.y = f2bf2(vr.a[ii][2].y, vr.a[ii][3].y);
        *(uint2*)&Vn[(d0 + 1) * VSTRIDE + kvb] = u;
        u.x = f2bf2(vr.a[ii][0].z, vr.a[ii][1].z); u.y = f2bf2(vr.a[ii][2].z, vr.a[ii][3].z);
        *(uint2*)&Vn[(d0 + 2) * VSTRIDE + kvb] = u;
        u.x = f2bf2(vr.a[ii][0].w, vr.a[ii][1].w); u.y = f2bf2(vr.a[ii][2].w, vr.a[ii][3].w);
        *(uint2*)&Vn[(d0 + 3) * VSTRIDE + kvb] = u;
    }
}

__global__ __launch_bounds__(256, 2) void sdpa_fwd_fb(
    const float* __restrict__ Qp, const float* __restrict__ Kp,
    const float* __restrict__ Vp, const int* __restrict__ Mp,
    float* __restrict__ Op)
{
    extern __shared__ unsigned char smem[];
    unsigned short* Kb   = (unsigned short*)smem;
    unsigned short* Vb   = (unsigned short*)(smem + KBYTES);
    float*          mlds = (float*)(smem + KBYTES + VBYTES);

    const int tid  = threadIdx.x;
    const int lane = tid & 63;
    const int wv   = tid >> 6;
    const int h    = lane >> 5;
    const int c31  = lane & 31;
    const int bid  = blockIdx.x;
    const int bh   = bid >> 4;
    const int q0   = (bid & 15) * FBQB;
    const int bb   = bh >> 4;
    const size_t base = (size_t)bh * S_LEN * D_DIM;

    constexpr float SC   = 0.08838834764831845f * 1.4426950408889634f;
    constexpr float NEGB = -1.4426950408889634e9f;
    constexpr float THR  = 11.541560327111708f;

    {
        const int* mp = Mp + bb * S_LEN;
#pragma unroll
        for (int i = 0; i < S_LEN / 256; ++i)
            mlds[tid + 256 * i] = mp[tid + 256 * i] ? 0.f : NEGB;
    }

    short8v qf[8];
    {
        const float* qrp = Qp + base + (size_t)(q0 + 32 * wv + c31) * D_DIM;
#pragma unroll
        for (int kk = 0; kk < 8; ++kk) {
            float4 x = *(const float4*)(qrp + 16 * kk + 8 * h);
            float4 y = *(const float4*)(qrp + 16 * kk + 8 * h + 4);
            uint4 w;
            w.x = f2bf2(x.x, x.y); w.y = f2bf2(x.z, x.w);
            w.z = f2bf2(y.x, y.y); w.w = f2bf2(y.z, y.w);
            *(uint4*)&qf[kk] = w;
        }
    }

    const int kc8 = tid & 15;
    const int kr0 = tid >> 4;
    const int vdg = tid & 31;
    const int vkq = tid >> 5;

    {
        KReg kr; VReg vr;
        load_K(kr, Kp + base, 0, kr0, kc8);
        load_V(vr, Vp + base, 0, vkq, vdg);
        write_K(kr, Kb, kr0, kc8);
        write_V(vr, Vb, vkq, vdg);
    }
    __syncthreads();

    f32x16 acc[4];
#pragma unroll
    for (int dt = 0; dt < 4; ++dt)
#pragma unroll
        for (int i = 0; i < 16; ++i) acc[dt][i] = 0.f;

    float m2 = -INFINITY;
    float lsum = 0.f;
    int cur = 0;

#pragma unroll 1
    for (int t0 = 0; t0 < FBNT; ++t0) {
        const int kv0 = t0 * FBKV;
        unsigned short* Kc = Kb + cur * KELEMS;
        unsigned short* Vc = Vb + cur * VELEMS;
        unsigned short* Kn = Kb + (cur ^ 1) * KELEMS;
        unsigned short* Vn = Vb + (cur ^ 1) * VELEMS;
        const bool pf = (t0 + 1 < FBNT);

        KReg kr; VReg vr;
        if (pf) {
            load_K(kr, Kp + base, kv0 + FBKV, kr0, kc8);
            load_V(vr, Vp + base, kv0 + FBKV, vkq, vdg);
        }

        f32x16 stc[2];
#pragma unroll
        for (int c = 0; c < 2; ++c) {
            f32x16 s;
#pragma unroll
            for (int i = 0; i < 16; ++i) s[i] = 0.f;
#pragma unroll
            for (int kk = 0; kk < 8; ++kk) {
                short8v kf = *(const short8v*)&Kc[(32 * c + c31) * KSTRIDE + 16 * kk + 8 * h];
                s = __builtin_amdgcn_mfma_f32_32x32x16_bf16(kf, qf[kk], s, 0, 0, 0);
            }
            stc[c] = s;
        }

        float p[2][16];
#pragma unroll
        for (int c = 0; c < 2; ++c)
#pragma unroll
            for (int t = 0; t < 4; ++t) {
                float4 b4 = *(const float4*)&mlds[kv0 + 32 * c + 8 * t + 4 * h];
                p[c][4 * t + 0] = fmaf(stc[c][4 * t + 0], SC, b4.x);
                p[c][4 * t + 1] = fmaf(stc[c][4 * t + 1], SC, b4.y);
                p[c][4 * t + 2] = fmaf(stc[c][4 * t + 2], SC, b4.z);
                p[c][4 * t + 3] = fmaf(stc[c][4 * t + 3], SC, b4.w);
            }

        float pmax = -INFINITY;
#pragma unroll
        for (int c = 0; c < 2; ++c)
#pragma unroll
            for (int r = 0; r < 16; ++r) pmax = fmaxf(pmax, p[c][r]);
        pmax = fmaxf(pmax, __shfl_xor(pmax, 32));
        if (!__all(pmax <= m2 + THR)) {
            float mnew = fmaxf(m2, pmax);
            float fr = __builtin_amdgcn_exp2f(m2 - mnew);
            m2 = mnew;
            lsum *= fr;
#pragma unroll
            for (int dt = 0; dt < 4; ++dt)
#pragma unroll
                for (int i = 0; i < 16; ++i) acc[dt][i] *= fr;
        }
        float ssum = 0.f;
#pragma unroll
        for (int c = 0; c < 2; ++c)
#pragma unroll
            for (int r = 0; r < 16; ++r) {
                float e = __builtin_amdgcn_exp2f(p[c][r] - m2);
                p[c][r] = e; ssum += e;
            }
        ssum += __shfl_xor(ssum, 32);
        lsum += ssum;

        unsigned w0[2][4], w1[2][4];
#pragma unroll
        for (int c = 0; c < 2; ++c)
#pragma unroll
            for (int t = 0; t < 4; ++t) {
                w0[c][t] = f2bf2(p[c][4 * t + 0], p[c][4 * t + 1]);
                w1[c][t] = f2bf2(p[c][4 * t + 2], p[c][4 * t + 3]);
            }

#pragma unroll
        for (int kk = 0; kk < 4; ++kk) {
            const int t0i = (2 * kk) & 3,     c0i = (2 * kk) >> 2;
            const int t1i = (2 * kk + 1) & 3, c1i = (2 * kk + 1) >> 2;
            unsigned own0 = h ? w0[c1i][t1i] : w0[c0i][t0i];
            unsigned own1 = h ? w1[c1i][t1i] : w1[c0i][t0i];
            unsigned snd0 = h ? w0[c0i][t0i] : w0[c1i][t1i];
            unsigned snd1 = h ? w1[c0i][t0i] : w1[c1i][t1i];
            unsigned r0 = __shfl_xor(snd0, 32);
            unsigned r1 = __shfl_xor(snd1, 32);
            uint4 pw;
            pw.x = h ? r0 : own0;  pw.y = h ? r1 : own1;
            pw.z = h ? own0 : r0;  pw.w = h ? own1 : r1;
            short8v pfv = *(short8v*)&pw;
#pragma unroll
            for (int dt = 0; dt < 4; ++dt) {
                short8v vf = *(const short8v*)&Vc[(32 * dt + c31) * VSTRIDE + 16 * kk + 8 * h];
                acc[dt] = __builtin_amdgcn_mfma_f32_32x32x16_bf16(vf, pfv, acc[dt], 0, 0, 0);
            }
        }

        if (pf) {
            write_K(kr, Kn, kr0, kc8);
            write_V(vr, Vn, vkq, vdg);
        }
        __syncthreads();
        cur ^= 1;
    }

    __syncthreads();
    const float linv = 1.0f / lsum;
    float* sw = (float*)(smem + wv * (32 * 68 * 4));
#pragma unroll
    for (int ph = 0; ph < 2; ++ph) {
#pragma unroll
        for (int dp = 0; dp < 2; ++dp) {
            const int dtg = 2 * ph + dp;
#pragma unroll
            for (int r = 0; r < 16; ++r) {
                int dloc = 32 * dp + (r & 3) + 8 * (r >> 2) + 4 * h;
                sw[c31 * 68 + dloc] = acc[dtg][r] * linv;
            }
        }
#pragma unroll
        for (int it = 0; it < 8; ++it) {
            int f4 = lane + 64 * it;
            int qq = f4 >> 4, c4 = f4 & 15;
            float4 val = *(const float4*)&sw[qq * 68 + 4 * c4];
            *(float4*)(Op + base + (size_t)(q0 + 32 * wv + qq) * D_DIM + 64 * ph + 4 * c4) = val;
        }
    }
}

extern "C" void kernel_launch(void* const* d_in, const int* in_sizes, int n_in,
                              void* d_out, int out_size, void* d_ws, size_t ws_size,
                              hipStream_t stream) {
    (void)in_sizes; (void)n_in; (void)out_size;
    const float* Q = (const float*)d_in[0];
    const float* K = (const float*)d_in[1];
    const float* V = (const float*)d_in[2];
    const int*   M = (const int*)d_in[3];
    float*       O = (float*)d_out;

    if (ws_size >= PRE_BYTES) {
        unsigned short* Kpre = (unsigned short*)d_ws;
        unsigned short* Vpre = (unsigned short*)((char*)d_ws + PRE_BYTES / 2);
        hipLaunchKernelGGL(preconv, dim3(64 * NT), dim3(256), 0, stream, K, V, Kpre, Vpre);
        hipLaunchKernelGGL(sdpa_fwd_pre, dim3(64 * (S_LEN / QBLK)), dim3(256), ASMEM, stream,
                           Q, Kpre, Vpre, M, O);
    } else {
        hipLaunchKernelGGL(sdpa_fwd_fb, dim3(1024), dim3(256), FBSMEM, stream, Q, K, V, M, O);
    }
}

// Round 13
// 190.610 us; speedup vs baseline: 1.0075x; 1.0075x over previous
//
#include <hip/hip_runtime.h>
#include <hip/hip_bf16.h>

#define S_LEN 2048
#define D_DIM 128
#define QBLK 128
#define KVBLK 64
#define NT (S_LEN / KVBLK)          // 32 tiles of 64 kv
#define KCHUNK 16384                // bytes per K tile image (64 rows x 256B)
#define VCHUNK 16384                // bytes per V^T tile image (128 d x 128B)
#define PRE_BYTES ((size_t)64 * NT * (KCHUNK + VCHUNK))   // 67108864

typedef __attribute__((ext_vector_type(8))) short short8v;
typedef __attribute__((ext_vector_type(16))) float f32x16;

static __device__ __forceinline__ unsigned f2bf2(float lo, float hi) {
    float2 f2; f2.x = lo; f2.y = hi;
    __hip_bfloat162 h2 = __float22bfloat162_rn(f2);   // v_cvt_pk_bf16_f32
    unsigned r;
    __builtin_memcpy(&r, &h2, 4);
    return r;
}

// SSA-pure permlane32_swap: new_a = {a.row0, b.row0}, new_b = {a.row1, b.row1}
static __device__ __forceinline__ void plswap(unsigned& a, unsigned& b) {
    auto r = __builtin_amdgcn_permlane32_swap(a, b, false, false);
    a = r[0]; b = r[1];
}
static __device__ __forceinline__ float plswap_sum(float x) {
    unsigned a = __float_as_uint(x), b = a;
    plswap(a, b);
    return __uint_as_float(a) + __uint_as_float(b);
}

static __device__ __forceinline__ void gload16(const void* g, void* l) {
    __builtin_amdgcn_global_load_lds(
        (const __attribute__((address_space(1))) unsigned int*)g,
        (__attribute__((address_space(3))) unsigned int*)l,
        16, 0, 0);
}

// stage one 16KB pre-swizzled chunk: wave-uniform LDS base, per-lane global addr
static __device__ __forceinline__ void stage16k(const unsigned char* g, unsigned char* l,
                                                int wv, int lane) {
#pragma unroll
    for (int i = 0; i < 4; ++i) {
        const int off = (wv * 4 + i) * 1024;
        gload16(g + off + lane * 16, l + off);
    }
}

// ============================================================================
// Kernel 1 (round-4 proven): pre-convert K -> bf16 swizzled image, V -> V^T
// K chunk: unit o=row*16+bs holds K[row][8b..], b=(bs&8)|((bs^row)&7)
// V chunk: unit o=d*8+bs holds V^T[d][8b..],   b=(bs^d)&7
// ============================================================================
#define VTS 133

__global__ __launch_bounds__(256) void preconv(
    const float* __restrict__ Kp, const float* __restrict__ Vp,
    unsigned short* __restrict__ Ko, unsigned short* __restrict__ Vo)
{
    __shared__ float vt[64 * VTS];
    const int tid = threadIdx.x;
    const int blk = blockIdx.x;          // bh*32 + t
    const size_t gbase = (size_t)(blk >> 5) * S_LEN * D_DIM + (size_t)(blk & 31) * KVBLK * D_DIM;

    // stage V fp32 64x128 tile into LDS
#pragma unroll
    for (int i = 0; i < 8; ++i) {
        int idx = (tid + 256 * i) * 4;
        int row = idx >> 7, col = idx & 127;
        float4 v4 = *(const float4*)(Vp + gbase + idx);
        float* d = &vt[row * VTS + col];
        d[0] = v4.x; d[1] = v4.y; d[2] = v4.z; d[3] = v4.w;
    }

    // K: direct convert + swizzle-store
    unsigned short* kout = Ko + (size_t)blk * 8192;
#pragma unroll
    for (int i = 0; i < 4; ++i) {
        int o = tid + 256 * i;
        int row = o >> 4, bs = o & 15;
        int b = (bs & 8) | ((bs ^ row) & 7);
        const float* gp = Kp + gbase + row * D_DIM + 8 * b;
        float4 x = *(const float4*)gp;
        float4 y = *(const float4*)(gp + 4);
        uint4 w;
        w.x = f2bf2(x.x, x.y); w.y = f2bf2(x.z, x.w);
        w.z = f2bf2(y.x, y.y); w.w = f2bf2(y.z, y.w);
        *(uint4*)(kout + o * 8) = w;
    }
    __syncthreads();

    // V^T: gather columns from LDS, swizzle-store
    unsigned short* vout = Vo + (size_t)blk * 8192;
#pragma unroll
    for (int i = 0; i < 4; ++i) {
        int o = tid + 256 * i;
        int d = o >> 3, bs = o & 7;
        int b = (bs ^ d) & 7;
        const float* c0 = &vt[(8 * b) * VTS + d];
        uint4 w;
        w.x = f2bf2(c0[0 * VTS], c0[1 * VTS]);
        w.y = f2bf2(c0[2 * VTS], c0[3 * VTS]);
        w.z = f2bf2(c0[4 * VTS], c0[5 * VTS]);
        w.w = f2bf2(c0[6 * VTS], c0[7 * VTS]);
        *(uint4*)(vout + o * 8) = w;
    }
}

// ============================================================================
// Kernel 2: fused attention, KVBLK=64, fixed-max softmax, permlane PV.
// Register-batch prefetch: 8 ds_read_b128 always in flight; next batch's
// loads issued BEFORE current batch's MFMAs. launch_bounds(256,2): LDS
// already caps at 2 blocks/CU, so spend the register budget on liveness.
// LDS: K dbuf 32KB | V dbuf 32KB | bias 8KB = 73728
// ============================================================================
#define ASMEM (32768 + 32768 + 8192)

__global__ __launch_bounds__(256, 2) void sdpa_fwd_pre(
    const float* __restrict__ Qp, const unsigned short* __restrict__ Kpre,
    const unsigned short* __restrict__ Vpre, const int* __restrict__ Mp,
    float* __restrict__ Op)
{
    extern __shared__ unsigned char smem[];
    unsigned char* KbB = smem;                     // [2][16384]
    unsigned char* VbB = smem + 32768;             // [2][16384]
    float* blds = (float*)(smem + 65536);          // [2048] additive bias (log2 units)

    const int tid  = threadIdx.x;
    const int lane = tid & 63;
    const int wv   = tid >> 6;
    const int h    = lane >> 5;
    const int c31  = lane & 31;
    const int hrx  = h ^ (c31 & 7);
    // XCD-aware bijective swizzle (1024 % 8 == 0)
    const int lbid = ((blockIdx.x & 7) << 7) | (blockIdx.x >> 3);
    const int bh   = lbid >> 4;
    const int q0   = (lbid & 15) * QBLK;
    const int bb   = bh >> 4;
    const size_t base = (size_t)bh * S_LEN * D_DIM;
    const unsigned char* Kg = (const unsigned char*)Kpre + (size_t)bh * (NT * KCHUNK);
    const unsigned char* Vg = (const unsigned char*)Vpre + (size_t)bh * (NT * VCHUNK);

    constexpr float SC   = 0.08838834764831845f * 1.4426950408889634f; // 1/sqrt(128)*log2e
    constexpr float NEGB = -1.4426950408889634e9f;                     // -1e9*log2e
    constexpr float M2   = 16.0f;  // fixed softmax stabilizer (log2 units)

    // ---- mask -> additive bias table: visible -> -M2, masked -> NEGB ----
    {
        const int* mp = Mp + bb * S_LEN;
#pragma unroll
        for (int i = 0; i < S_LEN / 256; ++i)
            blds[tid + 256 * i] = mp[tid + 256 * i] ? -M2 : NEGB;
    }

    // ---- Q fragments pre-scaled by SC: lane holds Q[q0+32*wv+c31][16*kk+8*h+j] ----
    short8v qf[8];
    {
        const float* qrp = Qp + base + (size_t)(q0 + 32 * wv + c31) * D_DIM;
#pragma unroll
        for (int kk = 0; kk < 8; ++kk) {
            float4 x = *(const float4*)(qrp + 16 * kk + 8 * h);
            float4 y = *(const float4*)(qrp + 16 * kk + 8 * h + 4);
            uint4 w;
            w.x = f2bf2(x.x * SC, x.y * SC); w.y = f2bf2(x.z * SC, x.w * SC);
            w.z = f2bf2(y.x * SC, y.y * SC); w.w = f2bf2(y.z * SC, y.w * SC);
            *(uint4*)&qf[kk] = w;
        }
    }

    // ---- prologue: stage tile 0 ----
    stage16k(Kg, KbB, wv, lane);
    stage16k(Vg, VbB, wv, lane);
    __syncthreads();

    f32x16 acc[4];   // O^T: rows d = 32*dt + rowmap, col q = c31
#pragma unroll
    for (int dt = 0; dt < 4; ++dt)
#pragma unroll
        for (int i = 0; i < 16; ++i) acc[dt][i] = 0.f;

    float lpA = 0.f, lpB = 0.f;
    int cur = 0;

#pragma unroll 1
    for (int t0 = 0; t0 < NT; ++t0) {
        const unsigned char* KcB = KbB + cur * KCHUNK;
        const unsigned char* VcB = VbB + cur * VCHUNK;

        // ---- issue next tile's gload_lds ----
        if (t0 + 1 < NT) {
            stage16k(Kg + (size_t)(t0 + 1) * KCHUNK, KbB + (cur ^ 1) * KCHUNK, wv, lane);
            stage16k(Vg + (size_t)(t0 + 1) * VCHUNK, VbB + (cur ^ 1) * VCHUNK, wv, lane);
        }

        const unsigned char* rowpA = KcB + (c31 << 8);
        const unsigned char* rowpB = KcB + ((32 + c31) << 8);

        // ---- C-init from bias (kv = 32c + 8t4 + 4h + j), both halves ----
        f32x16 sA, sB;
        {
            const float* bp = blds + t0 * KVBLK + 4 * h;
#pragma unroll
            for (int t4 = 0; t4 < 4; ++t4) {
                float4 b4 = *(const float4*)(bp + 8 * t4);
                sA[4 * t4 + 0] = b4.x; sA[4 * t4 + 1] = b4.y;
                sA[4 * t4 + 2] = b4.z; sA[4 * t4 + 3] = b4.w;
                float4 b5 = *(const float4*)(bp + 32 + 8 * t4);
                sB[4 * t4 + 0] = b5.x; sB[4 * t4 + 1] = b5.y;
                sB[4 * t4 + 2] = b5.z; sB[4 * t4 + 3] = b5.w;
            }
        }

        // ---- batch 0: load all 8 K(A) fragments (8 reads in flight) ----
        short8v kfA[8];
#pragma unroll
        for (int kk = 0; kk < 8; ++kk) {
            const int bs = ((2 * kk) & 8) | (((2 * kk) & 7) ^ hrx);
            kfA[kk] = *(const short8v*)(rowpA + (bs << 4));
        }

        // ---- batch 1 loads (K(B)) issued BEFORE MFMA-A consumes batch 0 ----
        short8v kfB[8];
#pragma unroll
        for (int kk = 0; kk < 8; ++kk) {
            const int bs = ((2 * kk) & 8) | (((2 * kk) & 7) ^ hrx);
            kfB[kk] = *(const short8v*)(rowpB + (bs << 4));
        }
#pragma unroll
        for (int kk = 0; kk < 8; ++kk)
            sA = __builtin_amdgcn_mfma_f32_32x32x16_bf16(kfA[kk], qf[kk], sA, 0, 0, 0);

        // ---- batch 2 loads (V ks=0,1) before MFMA-B ----
        short8v vf0[8];
#pragma unroll
        for (int ks = 0; ks < 2; ++ks) {
            const int bs = ((2 * ks) ^ hrx) & 7;
#pragma unroll
            for (int dt = 0; dt < 4; ++dt)
                vf0[4 * ks + dt] = *(const short8v*)(VcB + ((32 * dt + c31) << 7) + (bs << 4));
        }
#pragma unroll
        for (int kk = 0; kk < 8; ++kk)
            sB = __builtin_amdgcn_mfma_f32_32x32x16_bf16(kfB[kk], qf[kk], sB, 0, 0, 0);

        // ---- batch 3 loads (V ks=2,3) before exp(A) ----
        short8v vf1[8];
#pragma unroll
        for (int ks = 2; ks < 4; ++ks) {
            const int bs = ((2 * ks) ^ hrx) & 7;
#pragma unroll
            for (int dt = 0; dt < 4; ++dt)
                vf1[4 * (ks - 2) + dt] = *(const short8v*)(VcB + ((32 * dt + c31) << 7) + (bs << 4));
        }

        // ---- exp/pack(A) (overlaps batch-3 load latency) ----
        unsigned w0A[4], w1A[4];
        {
            float l0 = 0.f, l1 = 0.f;
#pragma unroll
            for (int t4 = 0; t4 < 4; ++t4) {
                float e0 = __builtin_amdgcn_exp2f(sA[4 * t4 + 0]);
                float e1 = __builtin_amdgcn_exp2f(sA[4 * t4 + 1]);
                float e2 = __builtin_amdgcn_exp2f(sA[4 * t4 + 2]);
                float e3 = __builtin_amdgcn_exp2f(sA[4 * t4 + 3]);
                w0A[t4] = f2bf2(e0, e1);
                w1A[t4] = f2bf2(e2, e3);
                l0 += e0 + e1; l1 += e2 + e3;
            }
            lpA += l0 + l1;
        }

        // ---- PV(ks=0,1 on A)  ||  exp/pack(B) ----
        unsigned w0B[4], w1B[4];
        {
            float l0 = 0.f, l1 = 0.f;
#pragma unroll
            for (int t4 = 0; t4 < 4; ++t4) {
                float f0 = __builtin_amdgcn_exp2f(sB[4 * t4 + 0]);
                float f1 = __builtin_amdgcn_exp2f(sB[4 * t4 + 1]);
                float f2 = __builtin_amdgcn_exp2f(sB[4 * t4 + 2]);
                float f3 = __builtin_amdgcn_exp2f(sB[4 * t4 + 3]);
                w0B[t4] = f2bf2(f0, f1);
                w1B[t4] = f2bf2(f2, f3);
                l0 += f0 + f1; l1 += f2 + f3;
            }
            lpB += l0 + l1;
        }
#pragma unroll
        for (int ks = 0; ks < 2; ++ks) {
            unsigned ax = w0A[2 * ks], bx = w0A[2 * ks + 1];
            plswap(ax, bx);
            unsigned ay = w1A[2 * ks], by = w1A[2 * ks + 1];
            plswap(ay, by);
            uint4 pw; pw.x = ax; pw.y = ay; pw.z = bx; pw.w = by;
            short8v pfv = *(short8v*)&pw;
#pragma unroll
            for (int dt = 0; dt < 4; ++dt)
                acc[dt] = __builtin_amdgcn_mfma_f32_32x32x16_bf16(vf0[4 * ks + dt], pfv, acc[dt], 0, 0, 0);
        }

        // ---- PV(ks=2,3 on B) ----
#pragma unroll
        for (int ks = 0; ks < 2; ++ks) {
            unsigned ax = w0B[2 * ks], bx = w0B[2 * ks + 1];
            plswap(ax, bx);
            unsigned ay = w1B[2 * ks], by = w1B[2 * ks + 1];
            plswap(ay, by);
            uint4 pw; pw.x = ax; pw.y = ay; pw.z = bx; pw.w = by;
            short8v pfv = *(short8v*)&pw;
#pragma unroll
            for (int dt = 0; dt < 4; ++dt)
                acc[dt] = __builtin_amdgcn_mfma_f32_32x32x16_bf16(vf1[4 * ks + dt], pfv, acc[dt], 0, 0, 0);
        }

        __syncthreads();   // drains vmcnt (prefetch landed) + all reads done
        cur ^= 1;
    }

    // ---- combine half-wave partial denoms; epilogue transpose + store ----
    const float linv = 1.0f / plswap_sum(lpA + lpB);
    float* sw = (float*)(smem + wv * (32 * 68 * 4));
#pragma unroll
    for (int ph = 0; ph < 2; ++ph) {
#pragma unroll
        for (int dp = 0; dp < 2; ++dp) {
            const int dtg = 2 * ph + dp;
#pragma unroll
            for (int r = 0; r < 16; ++r) {
                int dloc = 32 * dp + (r & 3) + 8 * (r >> 2) + 4 * h;
                sw[c31 * 68 + dloc] = acc[dtg][r] * linv;
            }
        }
#pragma unroll
        for (int it = 0; it < 8; ++it) {
            int f4 = lane + 64 * it;
            int qq = f4 >> 4, c4 = f4 & 15;
            float4 val = *(const float4*)&sw[qq * 68 + 4 * c4];
            *(float4*)(Op + base + (size_t)(q0 + 32 * wv + qq) * D_DIM + 64 * ph + 4 * c4) = val;
        }
    }
}

// ============================================================================
// Fallback (round-3 kernel, only if ws_size too small) — own constants
// ============================================================================
#define FBKV 64
#define FBNT (S_LEN / FBKV)
#define FBQB 128
#define KSTRIDE 136
#define VSTRIDE 72
#define KELEMS (FBKV * KSTRIDE)
#define VELEMS (D_DIM * VSTRIDE)
#define KBYTES (2 * KELEMS * 2)
#define VBYTES (2 * VELEMS * 2)
#define FBSMEM (KBYTES + VBYTES + S_LEN * 4)

struct KReg { float4 a[4][2]; };
struct VReg { float4 a[2][4]; };

static __device__ __forceinline__ void load_K(KReg& kr, const float* Kbase,
                                              int kv0, int kr0, int kc8) {
#pragma unroll
    for (int i = 0; i < 4; ++i) {
        const float* gp = Kbase + (size_t)(kv0 + kr0 + 16 * i) * D_DIM + 8 * kc8;
        kr.a[i][0] = *(const float4*)gp;
        kr.a[i][1] = *(const float4*)(gp + 4);
    }
}
static __device__ __forceinline__ void write_K(const KReg& kr, unsigned short* Kn,
                                               int kr0, int kc8) {
#pragma unroll
    for (int i = 0; i < 4; ++i) {
        uint4 w;
        w.x = f2bf2(kr.a[i][0].x, kr.a[i][0].y);
        w.y = f2bf2(kr.a[i][0].z, kr.a[i][0].w);
        w.z = f2bf2(kr.a[i][1].x, kr.a[i][1].y);
        w.w = f2bf2(kr.a[i][1].z, kr.a[i][1].w);
        *(uint4*)&Kn[(kr0 + 16 * i) * KSTRIDE + 8 * kc8] = w;
    }
}
static __device__ __forceinline__ void load_V(VReg& vr, const float* Vbase,
                                              int kv0, int vkq, int vdg) {
#pragma unroll
    for (int ii = 0; ii < 2; ++ii)
#pragma unroll
        for (int r = 0; r < 4; ++r)
            vr.a[ii][r] = *(const float4*)(Vbase + (size_t)(kv0 + 4 * vkq + 32 * ii + r) * D_DIM + 4 * vdg);
}
static __device__ __forceinline__ void write_V(const VReg& vr, unsigned short* Vn,
                                               int vkq, int vdg) {
#pragma unroll
    for (int ii = 0; ii < 2; ++ii) {
        const int kvb = 4 * vkq + 32 * ii;
        const int d0  = 4 * vdg;
        uint2 u;
        u.x = f2bf2(vr.a[ii][0].x, vr.a[ii][1].x); u.y = f2bf2(vr.a[ii][2].x, vr.a[ii][3].x);
        *(uint2*)&Vn[(d0 + 0) * VSTRIDE + kvb] = u;
        u.x = f2bf2(vr.a[ii][0].y, vr.a[ii][1].y); u.y = f2bf2(vr.a[ii][2].y, vr.a[ii][3].y);
        *(uint2*)&Vn[(d0 + 1) * VSTRIDE + kvb] = u;
        u.x = f2bf2(vr.a[ii][0].z, vr.a[ii][1].z); u.y = f2bf2(vr.a[ii][2].z, vr.a[ii][3].z);
        *(uint2*)&Vn[(d0 + 2) * VSTRIDE + kvb] = u;
        u.x = f2bf2(vr.a[ii][0].w, vr.a[ii][1].w); u.y = f2bf2(vr.a[ii][2].w, vr.a[ii][3].w);
        *(uint2*)&Vn[(d0 + 3) * VSTRIDE + kvb] = u;
    }
}

__global__ __launch_bounds__(256, 2) void sdpa_fwd_fb(
    const float* __restrict__ Qp, const float* __restrict__ Kp,
    const float* __restrict__ Vp, const int* __restrict__ Mp,
    float* __restrict__ Op)
{
    extern __shared__ unsigned char smem[];
    unsigned short* Kb   = (unsigned short*)smem;
    unsigned short* Vb   = (unsigned short*)(smem + KBYTES);
    float*          mlds = (float*)(smem + KBYTES + VBYTES);

    const int tid  = threadIdx.x;
    const int lane = tid & 63;
    const int wv   = tid >> 6;
    const int h    = lane >> 5;
    const int c31  = lane & 31;
    const int bid  = blockIdx.x;
    const int bh   = bid >> 4;
    const int q0   = (bid & 15) * FBQB;
    const int bb   = bh >> 4;
    const size_t base = (size_t)bh * S_LEN * D_DIM;

    constexpr float SC   = 0.08838834764831845f * 1.4426950408889634f;
    constexpr float NEGB = -1.4426950408889634e9f;
    constexpr float THR  = 11.541560327111708f;

    {
        const int* mp = Mp + bb * S_LEN;
#pragma unroll
        for (int i = 0; i < S_LEN / 256; ++i)
            mlds[tid + 256 * i] = mp[tid + 256 * i] ? 0.f : NEGB;
    }

    short8v qf[8];
    {
        const float* qrp = Qp + base + (size_t)(q0 + 32 * wv + c31) * D_DIM;
#pragma unroll
        for (int kk = 0; kk < 8; ++kk) {
            float4 x = *(const float4*)(qrp + 16 * kk + 8 * h);
            float4 y = *(const float4*)(qrp + 16 * kk + 8 * h + 4);
            uint4 w;
            w.x = f2bf2(x.x, x.y); w.y = f2bf2(x.z, x.w);
            w.z = f2bf2(y.x, y.y); w.w = f2bf2(y.z, y.w);
            *(uint4*)&qf[kk] = w;
        }
    }

    const int kc8 = tid & 15;
    const int kr0 = tid >> 4;
    const int vdg = tid & 31;
    const int vkq = tid >> 5;

    {
        KReg kr; VReg vr;
        load_K(kr, Kp + base, 0, kr0, kc8);
        load_V(vr, Vp + base, 0, vkq, vdg);
        write_K(kr, Kb, kr0, kc8);
        write_V(vr, Vb, vkq, vdg);
    }
    __syncthreads();

    f32x16 acc[4];
#pragma unroll
    for (int dt = 0; dt < 4; ++dt)
#pragma unroll
        for (int i = 0; i < 16; ++i) acc[dt][i] = 0.f;

    float m2 = -INFINITY;
    float lsum = 0.f;
    int cur = 0;

#pragma unroll 1
    for (int t0 = 0; t0 < FBNT; ++t0) {
        const int kv0 = t0 * FBKV;
        unsigned short* Kc = Kb + cur * KELEMS;
        unsigned short* Vc = Vb + cur * VELEMS;
        unsigned short* Kn = Kb + (cur ^ 1) * KELEMS;
        unsigned short* Vn = Vb + (cur ^ 1) * VELEMS;
        const bool pf = (t0 + 1 < FBNT);

        KReg kr; VReg vr;
        if (pf) {
            load_K(kr, Kp + base, kv0 + FBKV, kr0, kc8);
            load_V(vr, Vp + base, kv0 + FBKV, vkq, vdg);
        }

        f32x16 stc[2];
#pragma unroll
        for (int c = 0; c < 2; ++c) {
            f32x16 s;
#pragma unroll
            for (int i = 0; i < 16; ++i) s[i] = 0.f;
#pragma unroll
            for (int kk = 0; kk < 8; ++kk) {
                short8v kf = *(const short8v*)&Kc[(32 * c + c31) * KSTRIDE + 16 * kk + 8 * h];
                s = __builtin_amdgcn_mfma_f32_32x32x16_bf16(kf, qf[kk], s, 0, 0, 0);
            }
            stc[c] = s;
        }

        float p[2][16];
#pragma unroll
        for (int c = 0; c < 2; ++c)
#pragma unroll
            for (int t = 0; t < 4; ++t) {
                float4 b4 = *(const float4*)&mlds[kv0 + 32 * c + 8 * t + 4 * h];
                p[c][4 * t + 0] = fmaf(stc[c][4 * t + 0], SC, b4.x);
                p[c][4 * t + 1] = fmaf(stc[c][4 * t + 1], SC, b4.y);
                p[c][4 * t + 2] = fmaf(stc[c][4 * t + 2], SC, b4.z);
                p[c][4 * t + 3] = fmaf(stc[c][4 * t + 3], SC, b4.w);
            }

        float pmax = -INFINITY;
#pragma unroll
        for (int c = 0; c < 2; ++c)
#pragma unroll
            for (int r = 0; r < 16; ++r) pmax = fmaxf(pmax, p[c][r]);
        pmax = fmaxf(pmax, __shfl_xor(pmax, 32));
        if (!__all(pmax <= m2 + THR)) {
            float mnew = fmaxf(m2, pmax);
            float fr = __builtin_amdgcn_exp2f(m2 - mnew);
            m2 = mnew;
            lsum *= fr;
#pragma unroll
            for (int dt = 0; dt < 4; ++dt)
#pragma unroll
                for (int i = 0; i < 16; ++i) acc[dt][i] *= fr;
        }
        float ssum = 0.f;
#pragma unroll
        for (int c = 0; c < 2; ++c)
#pragma unroll
            for (int r = 0; r < 16; ++r) {
                float e = __builtin_amdgcn_exp2f(p[c][r] - m2);
                p[c][r] = e; ssum += e;
            }
        ssum += __shfl_xor(ssum, 32);
        lsum += ssum;

        unsigned w0[2][4], w1[2][4];
#pragma unroll
        for (int c = 0; c < 2; ++c)
#pragma unroll
            for (int t = 0; t < 4; ++t) {
                w0[c][t] = f2bf2(p[c][4 * t + 0], p[c][4 * t + 1]);
                w1[c][t] = f2bf2(p[c][4 * t + 2], p[c][4 * t + 3]);
            }

#pragma unroll
        for (int kk = 0; kk < 4; ++kk) {
            const int t0i = (2 * kk) & 3,     c0i = (2 * kk) >> 2;
            const int t1i = (2 * kk + 1) & 3, c1i = (2 * kk + 1) >> 2;
            unsigned own0 = h ? w0[c1i][t1i] : w0[c0i][t0i];
            unsigned own1 = h ? w1[c1i][t1i] : w1[c0i][t0i];
            unsigned snd0 = h ? w0[c0i][t0i] : w0[c1i][t1i];
            unsigned snd1 = h ? w1[c0i][t0i] : w1[c1i][t1i];
            unsigned r0 = __shfl_xor(snd0, 32);
            unsigned r1 = __shfl_xor(snd1, 32);
            uint4 pw;
            pw.x = h ? r0 : own0;  pw.y = h ? r1 : own1;
            pw.z = h ? own0 : r0;  pw.w = h ? own1 : r1;
            short8v pfv = *(short8v*)&pw;
#pragma unroll
            for (int dt = 0; dt < 4; ++dt) {
                short8v vf = *(const short8v*)&Vc[(32 * dt + c31) * VSTRIDE + 16 * kk + 8 * h];
                acc[dt] = __builtin_amdgcn_mfma_f32_32x32x16_bf16(vf, pfv, acc[dt], 0, 0, 0);
            }
        }

        if (pf) {
            write_K(kr, Kn, kr0, kc8);
            write_V(vr, Vn, vkq, vdg);
        }
        __syncthreads();
        cur ^= 1;
    }

    __syncthreads();
    const float linv = 1.0f / lsum;
    float* sw = (float*)(smem + wv * (32 * 68 * 4));
#pragma unroll
    for (int ph = 0; ph < 2; ++ph) {
#pragma unroll
        for (int dp = 0; dp < 2; ++dp) {
            const int dtg = 2 * ph + dp;
#pragma unroll
            for (int r = 0; r < 16; ++r) {
                int dloc = 32 * dp + (r & 3) + 8 * (r >> 2) + 4 * h;
                sw[c31 * 68 + dloc] = acc[dtg][r] * linv;
            }
        }
#pragma unroll
        for (int it = 0; it < 8; ++it) {
            int f4 = lane + 64 * it;
            int qq = f4 >> 4, c4 = f4 & 15;
            float4 val = *(const float4*)&sw[qq * 68 + 4 * c4];
            *(float4*)(Op + base + (size_t)(q0 + 32 * wv + qq) * D_DIM + 64 * ph + 4 * c4) = val;
        }
    }
}

extern "C" void kernel_launch(void* const* d_in, const int* in_sizes, int n_in,
                              void* d_out, int out_size, void* d_ws, size_t ws_size,
                              hipStream_t stream) {
    (void)in_sizes; (void)n_in; (void)out_size;
    const float* Q = (const float*)d_in[0];
    const float* K = (const float*)d_in[1];
    const float* V = (const float*)d_in[2];
    const int*   M = (const int*)d_in[3];
    float*       O = (float*)d_out;

    if (ws_size >= PRE_BYTES) {
        unsigned short* Kpre = (unsigned short*)d_ws;
        unsigned short* Vpre = (unsigned short*)((char*)d_ws + PRE_BYTES / 2);
        hipLaunchKernelGGL(preconv, dim3(64 * NT), dim3(256), 0, stream, K, V, Kpre, Vpre);
        hipLaunchKernelGGL(sdpa_fwd_pre, dim3(64 * (S_LEN / QBLK)), dim3(256), ASMEM, stream,
                           Q, Kpre, Vpre, M, O);
    } else {
        hipLaunchKernelGGL(sdpa_fwd_fb, dim3(1024), dim3(256), FBSMEM, stream, Q, K, V, M, O);
    }
}